// Round 4
// baseline (170.537 us; speedup 1.0000x reference)
//
#include <hip/hip_runtime.h>
#include <hip/hip_bf16.h>

#define BATCH 4
#define NTOK 4096
#define CDIM 128
#define KSCALE 0.02254211001389005f   // log2(e)/64  (scale = 1/sqrt(4096), ref quirk)

typedef __bf16 bf16;
typedef __bf16 bf16x8 __attribute__((ext_vector_type(8)));
typedef __bf16 bf16x4 __attribute__((ext_vector_type(4)));
typedef float  f32x4  __attribute__((ext_vector_type(4)));

// K tile image (64 token-rows x 128 ch): 8-elem segments, XOR-swizzled so
// attn's B-frag reads (16 lanes -> 16 consecutive rows) are conflict-free AND
// proj's C-layout scatter (quads -> rows +4 apart) is conflict-free (r>>2 term).
__device__ __forceinline__ int koff(int r, int c) {
    return (r * 16 + (((c >> 3) ^ r ^ (r >> 2)) & 15)) * 8 + (c & 7);
}
// V tile image (kv contiguous within 8-elem segment; segment = kv-group major)
__device__ __forceinline__ int voff(int d, int kv) {
    return ((kv >> 3) * 128 + (d ^ (kv >> 3))) * 8 + (kv & 7);
}

__device__ __forceinline__ void dma16(const bf16* g, bf16* l) {
    __builtin_amdgcn_global_load_lds(
        (const __attribute__((address_space(1))) unsigned int*)g,
        (__attribute__((address_space(3))) unsigned int*)l, 16, 0, 0);
}

// ---------------------------------------------------------------------------
// Projection. grid (64 n-tiles, B, 3), block 256. m=z selects Wq/Wk/Wv.
// Q -> linear [B][N][C]; K,V -> per-tile swizzled LDS images (attn DMAs them
// linearly). All global writes coalesced b128 via LDS roundtrip (t_s reuse).
// LDS 50 KB -> 3 blocks/CU.
// ---------------------------------------------------------------------------
__global__ __launch_bounds__(256) void proj_kernel(
    const float* __restrict__ x, const float* __restrict__ Wq,
    const float* __restrict__ Wk, const float* __restrict__ Wv,
    bf16* __restrict__ Qg, bf16* __restrict__ Kg, bf16* __restrict__ Vtg)
{
    __shared__ bf16 t_s[64 * 136];    // x tile transposed; reused as output image
    __shared__ bf16 w_s[128 * 128];   // W, segment-swizzled

    const int tid = threadIdx.x;
    const int b = blockIdx.y, n0 = blockIdx.x * 64, m = blockIdx.z;
    const float* W = (m == 0) ? Wq : (m == 1) ? Wk : Wv;

    {   // stage x[b,:,n0:n0+64] transposed -> t_s[n][c]
        const float* xb = x + (size_t)b * CDIM * NTOK + n0;
        const int n = tid & 63, cg4 = tid >> 6;
#pragma unroll
        for (int g = 0; g < 8; ++g) {
            const int c0 = g * 16 + cg4 * 4;
            float v0 = xb[(size_t)(c0 + 0) * NTOK + n];
            float v1 = xb[(size_t)(c0 + 1) * NTOK + n];
            float v2 = xb[(size_t)(c0 + 2) * NTOK + n];
            float v3 = xb[(size_t)(c0 + 3) * NTOK + n];
            bf16x4 t = {(bf16)v0, (bf16)v1, (bf16)v2, (bf16)v3};
            *(bf16x4*)&t_s[n * 136 + c0] = t;
        }
    }
    {   // stage W swizzled (R2 pattern, measured 0 conflicts)
#pragma unroll
        for (int it = 0; it < 16; ++it) {
            const int idx = it * 1024 + tid * 4;
            const int d = idx >> 7, c = idx & 127;
            const float4 v = *(const float4*)(W + d * 128 + c);
            bf16x4 t = {(bf16)v.x, (bf16)v.y, (bf16)v.z, (bf16)v.w};
            *(bf16x4*)&w_s[(d * 16 + (((c >> 3) ^ d) & 15)) * 8 + (c & 7)] = t;
        }
    }
    __syncthreads();

    const int lane = tid & 63, wv = tid >> 6;
    const int l16 = lane & 15, quad = lane >> 4;

    bf16x8 af[4];
#pragma unroll
    for (int kc = 0; kc < 4; ++kc)
        af[kc] = *(const bf16x8*)&t_s[(wv * 16 + l16) * 136 + kc * 32 + quad * 8];
    __syncthreads();                 // t_s free -> output image
    bf16* img = t_s;

#pragma unroll
    for (int dblk = 0; dblk < 8; ++dblk) {
        f32x4 acc = {0.f, 0.f, 0.f, 0.f};
#pragma unroll
        for (int kc = 0; kc < 4; ++kc) {
            const int seg = (dblk * 16 + l16) * 16 + (((kc * 4 + quad) ^ l16) & 15);
            acc = __builtin_amdgcn_mfma_f32_16x16x32_bf16(
                af[kc], *(const bf16x8*)&w_s[seg * 8], acc, 0, 0, 0);
        }
#pragma unroll
        for (int i = 0; i < 4; ++i) {
            const int r = wv * 16 + quad * 4 + i;   // token
            const int c = dblk * 16 + l16;          // channel
            if (m == 2) img[voff(c, r)] = (bf16)acc[i];
            else        img[koff(r, c)] = (bf16)acc[i];
        }
    }
    __syncthreads();

    if (m == 0) {   // unswizzle -> Qg linear
        const int r = tid >> 2, q4 = tid & 3;
        bf16* dst = Qg + ((size_t)b * NTOK + n0 + r) * CDIM + q4 * 32;
#pragma unroll
        for (int j = 0; j < 4; ++j)
            *(bf16x8*)(dst + j * 8) = *(const bf16x8*)&img[koff(r, q4 * 32 + j * 8)];
    } else {        // dump image verbatim (attn stages it linearly via DMA)
        bf16* dst = ((m == 1) ? Kg : Vtg) + ((size_t)b * 64 + blockIdx.x) * 8192 + tid * 32;
#pragma unroll
        for (int j = 0; j < 4; ++j)
            *(bf16x8*)(dst + j * 8) = *(const bf16x8*)&img[tid * 32 + j * 8];
    }
}

// ---------------------------------------------------------------------------
// Flash attention, no-max softmax. Q-tile 128/block, wave owns 32 rows
// (rb=0,1): K/V LDS reads amortized over 2x MFMA vs R2. K/V staged by
// global_load_lds width-16 DMA from pre-swizzled images. LDS 48 KB.
// Writes bf16 unnormalized partials in C-fragment order (coalesced) + row sums.
// ---------------------------------------------------------------------------
__global__ __launch_bounds__(256) void attn_kernel(
    const bf16* __restrict__ Qg, const bf16* __restrict__ Kg,
    const bf16* __restrict__ Vtg, bf16* __restrict__ Op,
    float* __restrict__ lsum, int nsplit)
{
    __shared__ bf16 k2[8192];
    __shared__ bf16 vt2[8192];
    __shared__ bf16 p_s[4][2][1024];   // per wave, per row-block

    const int tid = threadIdx.x;
    const int qb = blockIdx.x, b = blockIdx.y, sp = blockIdx.z;
    const int q0 = qb * 128;
    const int lane = tid & 63, wv = tid >> 6;
    const int l16 = lane & 15, quad = lane >> 4;
    const int ktn = 64 / nsplit, kt0 = sp * ktn;

    bf16x8 af[2][4];
#pragma unroll
    for (int rb = 0; rb < 2; ++rb)
#pragma unroll
        for (int kc = 0; kc < 4; ++kc)
            af[rb][kc] = *(const bf16x8*)&Qg[((size_t)b * NTOK + q0 + wv * 32 + rb * 16 + l16) * CDIM
                                             + kc * 32 + quad * 8];

    f32x4 o[2][8];
#pragma unroll
    for (int rb = 0; rb < 2; ++rb)
#pragma unroll
        for (int d = 0; d < 8; ++d) o[rb][d] = (f32x4){0.f, 0.f, 0.f, 0.f};
    float ls[2][4] = {{0.f,0.f,0.f,0.f},{0.f,0.f,0.f,0.f}};

    for (int kt = kt0; kt < kt0 + ktn; ++kt) {
        const bf16* Kt = Kg  + ((size_t)b * 64 + kt) * 8192;
        const bf16* Vt = Vtg + ((size_t)b * 64 + kt) * 8192;
#pragma unroll
        for (int i = 0; i < 4; ++i) {
            const int seg = wv * 4 + i;         // 1024-B chunk
            dma16(Kt + seg * 512 + lane * 8, &k2[seg * 512 + lane * 8]);
            dma16(Vt + seg * 512 + lane * 8, &vt2[seg * 512 + lane * 8]);
        }
        __syncthreads();

        // S = Q K^T, softmax'd per 16-col block; bk shared across both rbs.
        // BUGFIX vs R3: the koff XOR term (rr ^ (rr>>2)) & 15 DEPENDS on nb
        // ((rr>>2)&15 = nb*4 + (l16>>2)) — use the full expression, no
        // "l16-only" shortcut. nb is a compile-time unroll constant anyway.
#pragma unroll
        for (int nb = 0; nb < 4; ++nb) {
            const int rr  = nb * 16 + l16;      // K token row
            const int rsw = (rr ^ (rr >> 2)) & 15;
            f32x4 s0 = {0.f,0.f,0.f,0.f}, s1 = {0.f,0.f,0.f,0.f};
#pragma unroll
            for (int kc = 0; kc < 4; ++kc) {
                bf16x8 bk = *(const bf16x8*)&k2[(rr * 16 + (((kc * 4 + quad) ^ rsw) & 15)) * 8];
                s0 = __builtin_amdgcn_mfma_f32_16x16x32_bf16(af[0][kc], bk, s0, 0, 0, 0);
                s1 = __builtin_amdgcn_mfma_f32_16x16x32_bf16(af[1][kc], bk, s1, 0, 0, 0);
            }
            const int col = nb * 16 + l16;
#pragma unroll
            for (int i = 0; i < 4; ++i) {
                const int row = quad * 4 + i;
                const int idx = (row * 8 + (((col >> 3) ^ row) & 7)) * 8 + (col & 7);
                float p0 = __builtin_amdgcn_exp2f(s0[i] * KSCALE); ls[0][i] += p0;
                float p1 = __builtin_amdgcn_exp2f(s1[i] * KSCALE); ls[1][i] += p1;
                p_s[wv][0][idx] = (bf16)p0;
                p_s[wv][1][idx] = (bf16)p1;
            }
        }

        // P fragments (wave-private buffers; lgkmcnt ordering suffices)
        bf16x8 pf[2][2];
#pragma unroll
        for (int rb = 0; rb < 2; ++rb)
#pragma unroll
            for (int kc = 0; kc < 2; ++kc) {
                const int kvg = kc * 4 + quad;
                pf[rb][kc] = *(const bf16x8*)&p_s[wv][rb][(l16 * 8 + ((kvg ^ l16) & 7)) * 8];
            }

        // O += P V ; bv shared across both rbs
#pragma unroll
        for (int kc = 0; kc < 2; ++kc) {
            const int kvg = kc * 4 + quad;
#pragma unroll
            for (int d = 0; d < 8; ++d) {
                bf16x8 bv = *(const bf16x8*)&vt2[(kvg * 128 + ((d * 16 + l16) ^ kvg)) * 8];
                o[0][d] = __builtin_amdgcn_mfma_f32_16x16x32_bf16(pf[0][kc], bv, o[0][d], 0, 0, 0);
                o[1][d] = __builtin_amdgcn_mfma_f32_16x16x32_bf16(pf[1][kc], bv, o[1][d], 0, 0, 0);
            }
        }
        __syncthreads();   // protect k2/vt2 before next DMA
    }

    // row sums across the 16 lanes of each quad
#pragma unroll
    for (int rb = 0; rb < 2; ++rb)
#pragma unroll
        for (int i = 0; i < 4; ++i)
#pragma unroll
            for (int off = 1; off < 16; off <<= 1)
                ls[rb][i] += __shfl_xor(ls[rb][i], off, 64);
    if (l16 == 0) {
#pragma unroll
        for (int rb = 0; rb < 2; ++rb)
#pragma unroll
            for (int i = 0; i < 4; ++i)
                lsum[(size_t)sp * (BATCH * NTOK) + (size_t)b * NTOK
                     + q0 + wv * 32 + rb * 16 + quad * 4 + i] = ls[rb][i];
    }
    // bf16 partials in fragment order: [sp][qb][b][wv][rb][d][i][lane] (coalesced)
    bf16* op = Op + (((((size_t)sp * 32 + qb) * BATCH + b) * 4 + wv) * (2 * 8 * 4 * 64));
#pragma unroll
    for (int rb = 0; rb < 2; ++rb)
#pragma unroll
        for (int d = 0; d < 8; ++d)
#pragma unroll
            for (int i = 0; i < 4; ++i)
                op[((rb * 8 + d) * 4 + i) * 64 + lane] = (bf16)o[rb][d][i];
}

// ---------------------------------------------------------------------------
// Combine: out = sum_sp(Op) / sum_sp(lsum), decoding the fragment order.
// ---------------------------------------------------------------------------
__global__ __launch_bounds__(256) void combine_kernel(
    const bf16* __restrict__ Op, const float* __restrict__ lsum,
    float* __restrict__ out, int nsplit)
{
    const int g = blockIdx.x * 256 + threadIdx.x;
    const int lane = g & 63;
    const int wt = g >> 6;             // [0, 32768)
    const int i  = wt & 3;
    const int d  = (wt >> 2) & 7;
    const int rb = (wt >> 5) & 1;
    const int wv = (wt >> 6) & 3;
    const int b  = (wt >> 8) & 3;
    const int qb = wt >> 10;

    const size_t spstride = (size_t)32 * BATCH * 4 * 2 * 8 * 4 * 64;  // 2M elems
    float acc = 0.f;
    for (int s = 0; s < nsplit; ++s)
        acc += (float)Op[(size_t)s * spstride + (size_t)wt * 64 + lane];
    const int row = qb * 128 + wv * 32 + rb * 16 + (lane >> 4) * 4 + i;
    float l = 0.f;
    for (int s = 0; s < nsplit; ++s)
        l += lsum[(size_t)s * (BATCH * NTOK) + b * NTOK + row];
    out[((size_t)b * NTOK + row) * CDIM + d * 16 + (lane & 15)] = acc / l;
}

// ---------------------------------------------------------------------------
extern "C" void kernel_launch(void* const* d_in, const int* in_sizes, int n_in,
                              void* d_out, int out_size, void* d_ws, size_t ws_size,
                              hipStream_t stream)
{
    const float* x  = (const float*)d_in[0];
    const float* Wq = (const float*)d_in[1];
    const float* Wk = (const float*)d_in[2];
    const float* Wv = (const float*)d_in[3];
    float* out = (float*)d_out;

    // ws: Q 4M | K 4M | Vt 4M | lsum 512K | Op nsplit*4M (bf16)
    char* ws = (char*)d_ws;
    bf16*  Qg   = (bf16*)ws;
    bf16*  Kg   = (bf16*)(ws + (4u << 20));
    bf16*  Vtg  = (bf16*)(ws + (8u << 20));
    float* lsum = (float*)(ws + (12u << 20));
    bf16*  Op   = (bf16*)(ws + (12u << 20) + (512u << 10));

    const size_t base = (12u << 20) + (512u << 10);
    const size_t MB4  = 4u << 20;
    int nsplit = (ws_size >= base + 8 * MB4) ? 8
               : (ws_size >= base + 4 * MB4) ? 4 : 2;

    hipLaunchKernelGGL(proj_kernel, dim3(64, BATCH, 3), dim3(256), 0, stream,
                       x, Wq, Wk, Wv, Qg, Kg, Vtg);
    hipLaunchKernelGGL(attn_kernel, dim3(32, BATCH, nsplit), dim3(256), 0, stream,
                       Qg, Kg, Vtg, Op, lsum, nsplit);
    hipLaunchKernelGGL(combine_kernel, dim3(8192), dim3(256), 0, stream,
                       Op, lsum, out, nsplit);
}

// Round 6
// 164.520 us; speedup vs baseline: 1.0366x; 1.0366x over previous
//
#include <hip/hip_runtime.h>
#include <hip/hip_bf16.h>

#define BATCH 4
#define NTOK 4096
#define CDIM 128
#define KSCALE 0.02254211001389005f   // log2(e)/64  (scale = 1/sqrt(4096), ref quirk)

typedef __bf16 bf16;
typedef __bf16 bf16x8 __attribute__((ext_vector_type(8)));
typedef __bf16 bf16x4 __attribute__((ext_vector_type(4)));
typedef float  f32x4  __attribute__((ext_vector_type(4)));

// K tile image (64 token-rows x 128 ch): 8-elem segments, XOR-swizzled (R4-verified).
__device__ __forceinline__ int koff(int r, int c) {
    return (r * 16 + (((c >> 3) ^ r ^ (r >> 2)) & 15)) * 8 + (c & 7);
}
// V tile image (kv contiguous within 8-elem segment) (R4-verified).
__device__ __forceinline__ int voff(int d, int kv) {
    return ((kv >> 3) * 128 + (d ^ (kv >> 3))) * 8 + (kv & 7);
}

__device__ __forceinline__ void dma16(const bf16* g, bf16* l) {
    __builtin_amdgcn_global_load_lds(
        (const __attribute__((address_space(1))) unsigned int*)g,
        (__attribute__((address_space(3))) unsigned int*)l, 16, 0, 0);
}

// ---------------------------------------------------------------------------
// Prep: convert Wq/Wk/Wv fp32 -> swizzled bf16 images (proj DMAs them).
// ---------------------------------------------------------------------------
__global__ __launch_bounds__(256) void prep_kernel(
    const float* __restrict__ Wq, const float* __restrict__ Wk,
    const float* __restrict__ Wv, bf16* __restrict__ Wimg)
{
    const int m = blockIdx.y;
    const float* W = (m == 0) ? Wq : (m == 1) ? Wk : Wv;
    const int idx = blockIdx.x * 1024 + threadIdx.x * 4;
    const int d = idx >> 7, c = idx & 127;
    const float4 v = *(const float4*)(W + d * 128 + c);
    bf16x4 t = {(bf16)v.x, (bf16)v.y, (bf16)v.z, (bf16)v.w};
    *(bf16x4*)&Wimg[m * 16384 + (d * 16 + (((c >> 3) ^ d) & 15)) * 8 + (c & 7)] = t;
}

// ---------------------------------------------------------------------------
// Projection. grid (64 n-tiles, B, 3), block 256. m selects Wq/Wk/Wv.
// W staged by DMA from the prep image. Q -> linear [B][N][C]; K,V ->
// per-tile swizzled images for attn's DMA. LDS 49.4K -> 3 blocks/CU.
// ---------------------------------------------------------------------------
__global__ __launch_bounds__(256) void proj_kernel(
    const float* __restrict__ x, const bf16* __restrict__ Wimg,
    bf16* __restrict__ Qg, bf16* __restrict__ Kg, bf16* __restrict__ Vtg)
{
    __shared__ bf16 t_s[64 * 136];    // x tile transposed; reused as output image
    __shared__ bf16 w_s[128 * 128];   // W image (DMA'd verbatim)

    const int tid = threadIdx.x;
    const int b = blockIdx.y, n0 = blockIdx.x * 64, m = blockIdx.z;
    const int lane = tid & 63, wv = tid >> 6;

    {   // DMA the 32KB W image: 32 chunks of 1KB (512 elems each), 8 per wave
        const bf16* wim = Wimg + m * 16384;
#pragma unroll
        for (int i = 0; i < 8; ++i) {
            const int off = (wv * 8 + i) * 512 + lane * 8;
            dma16(wim + off, &w_s[off]);
        }
    }
    {   // stage x[b,:,n0:n0+64] transposed -> t_s[n][c] (R2/R4-verified)
        const float* xb = x + (size_t)b * CDIM * NTOK + n0;
        const int n = tid & 63, cg4 = tid >> 6;
#pragma unroll
        for (int g = 0; g < 8; ++g) {
            const int c0 = g * 16 + cg4 * 4;
            float v0 = xb[(size_t)(c0 + 0) * NTOK + n];
            float v1 = xb[(size_t)(c0 + 1) * NTOK + n];
            float v2 = xb[(size_t)(c0 + 2) * NTOK + n];
            float v3 = xb[(size_t)(c0 + 3) * NTOK + n];
            bf16x4 t = {(bf16)v0, (bf16)v1, (bf16)v2, (bf16)v3};
            *(bf16x4*)&t_s[n * 136 + c0] = t;
        }
    }
    __syncthreads();   // full drain (vmcnt for DMA + lgkm) — wanted here

    const int l16 = lane & 15, quad = lane >> 4;

    bf16x8 af[4];
#pragma unroll
    for (int kc = 0; kc < 4; ++kc)
        af[kc] = *(const bf16x8*)&t_s[(wv * 16 + l16) * 136 + kc * 32 + quad * 8];
    __syncthreads();                 // t_s free -> output image
    bf16* img = t_s;

#pragma unroll
    for (int dblk = 0; dblk < 8; ++dblk) {
        f32x4 acc = {0.f, 0.f, 0.f, 0.f};
#pragma unroll
        for (int kc = 0; kc < 4; ++kc) {
            const int seg = (dblk * 16 + l16) * 16 + (((kc * 4 + quad) ^ l16) & 15);
            acc = __builtin_amdgcn_mfma_f32_16x16x32_bf16(
                af[kc], *(const bf16x8*)&w_s[seg * 8], acc, 0, 0, 0);
        }
#pragma unroll
        for (int i = 0; i < 4; ++i) {
            const int r = wv * 16 + quad * 4 + i;   // token
            const int c = dblk * 16 + l16;          // channel
            if (m == 2) img[voff(c, r)] = (bf16)acc[i];
            else        img[koff(r, c)] = (bf16)acc[i];
        }
    }
    __syncthreads();

    if (m == 0) {   // unswizzle -> Qg linear
        const int r = tid >> 2, q4 = tid & 3;
        bf16* dst = Qg + ((size_t)b * NTOK + n0 + r) * CDIM + q4 * 32;
#pragma unroll
        for (int j = 0; j < 4; ++j)
            *(bf16x8*)(dst + j * 8) = *(const bf16x8*)&img[koff(r, q4 * 32 + j * 8)];
    } else {        // dump image verbatim
        bf16* dst = ((m == 1) ? Kg : Vtg) + ((size_t)b * 64 + blockIdx.x) * 8192 + tid * 32;
#pragma unroll
        for (int j = 0; j < 4; ++j)
            *(bf16x8*)(dst + j * 8) = *(const bf16x8*)&img[tid * 32 + j * 8];
    }
}

// ---------------------------------------------------------------------------
// Flash attention, no-max softmax, software-pipelined DMA.
// Per iter: barA | issue V(t+1)->vt2[^] | vmcnt(4) barB | S(t) [k2] | barC |
// issue K(t+1)->k2 | PV rb0 | scatter p1 | PV rb1.
// vmcnt never drains to 0 mid-loop. LDS = 16K + 32K + 8K = 56K.
// BUGFIX vs R5: DMA chunk stride is 512 elems (1KB), not 2048 — R5 wrote
// 3/4 garbage and stomped past the LDS allocation (NaN source).
// ---------------------------------------------------------------------------
__global__ __launch_bounds__(256) void attn_kernel(
    const bf16* __restrict__ Qg, const bf16* __restrict__ Kg,
    const bf16* __restrict__ Vtg, bf16* __restrict__ Op,
    float* __restrict__ lsum, int nsplit)
{
    __shared__ bf16 k2[8192];
    __shared__ bf16 vt2[2][8192];
    __shared__ bf16 p_s[4][1024];   // per wave, reused for rb0 then rb1

    const int tid = threadIdx.x;
    const int qb = blockIdx.x, b = blockIdx.y, sp = blockIdx.z;
    const int q0 = qb * 128;
    const int lane = tid & 63, wv = tid >> 6;
    const int l16 = lane & 15, quad = lane >> 4;
    const int ktn = 64 / nsplit, kt0 = sp * ktn, kend = kt0 + ktn;

    bf16x8 af[2][4];
#pragma unroll
    for (int rb = 0; rb < 2; ++rb)
#pragma unroll
        for (int kc = 0; kc < 4; ++kc)
            af[rb][kc] = *(const bf16x8*)&Qg[((size_t)b * NTOK + q0 + wv * 32 + rb * 16 + l16) * CDIM
                                             + kc * 32 + quad * 8];

    f32x4 o[2][8];
#pragma unroll
    for (int rb = 0; rb < 2; ++rb)
#pragma unroll
        for (int d = 0; d < 8; ++d) o[rb][d] = (f32x4){0.f, 0.f, 0.f, 0.f};
    float ls[2][4] = {{0.f,0.f,0.f,0.f},{0.f,0.f,0.f,0.f}};

    const int doff = lane * 8;   // per-lane elem offset inside a 1KB (512-elem) chunk

    // Prologue: V(kt0) then K(kt0)  (queue order matters for vmcnt math)
    {
        const bf16* Vt = Vtg + ((size_t)b * 64 + kt0) * 8192;
        const bf16* Kt = Kg  + ((size_t)b * 64 + kt0) * 8192;
#pragma unroll
        for (int i = 0; i < 4; ++i) {
            const int off = (wv * 4 + i) * 512 + doff;   // 4 chunks/wave, 512-elem stride
            dma16(Vt + off, &vt2[kt0 & 1][off]);
        }
#pragma unroll
        for (int i = 0; i < 4; ++i) {
            const int off = (wv * 4 + i) * 512 + doff;
            dma16(Kt + off, &k2[off]);
        }
    }

    for (int kt = kt0; kt < kend; ++kt) {
        const int cur = kt & 1;
        const bool more = (kt + 1 < kend);

        __builtin_amdgcn_sched_barrier(0);
        __builtin_amdgcn_s_barrier();                 // barA: vt2[1-cur] free
        __builtin_amdgcn_sched_barrier(0);
        if (more) {
            const bf16* Vn = Vtg + ((size_t)b * 64 + kt + 1) * 8192;
#pragma unroll
            for (int i = 0; i < 4; ++i) {
                const int off = (wv * 4 + i) * 512 + doff;
                dma16(Vn + off, &vt2[1 - cur][off]);
            }
        }
        __builtin_amdgcn_sched_barrier(0);
        if (more) __builtin_amdgcn_s_waitcnt(0xF74);  // vmcnt(4): V(t),K(t) done
        else      __builtin_amdgcn_s_waitcnt(0xF70);  // vmcnt(0): last tile
        __builtin_amdgcn_s_barrier();                 // barB: tile t in LDS
        __builtin_amdgcn_sched_barrier(0);

        // ---- S phase: S = Q K^T for both row-blocks (bk shared) ----
        float p1f[4][4];
#pragma unroll
        for (int nb = 0; nb < 4; ++nb) {
            const int rr  = nb * 16 + l16;
            const int rsw = (rr ^ (rr >> 2)) & 15;
            f32x4 s0 = {0.f,0.f,0.f,0.f}, s1 = {0.f,0.f,0.f,0.f};
#pragma unroll
            for (int kc = 0; kc < 4; ++kc) {
                bf16x8 bk = *(const bf16x8*)&k2[(rr * 16 + (((kc * 4 + quad) ^ rsw) & 15)) * 8];
                s0 = __builtin_amdgcn_mfma_f32_16x16x32_bf16(af[0][kc], bk, s0, 0, 0, 0);
                s1 = __builtin_amdgcn_mfma_f32_16x16x32_bf16(af[1][kc], bk, s1, 0, 0, 0);
            }
            const int col = nb * 16 + l16;
#pragma unroll
            for (int i = 0; i < 4; ++i) {
                const int row = quad * 4 + i;
                const int idx = (row * 8 + (((col >> 3) ^ row) & 7)) * 8 + (col & 7);
                float p0 = __builtin_amdgcn_exp2f(s0[i] * KSCALE); ls[0][i] += p0;
                float p1 = __builtin_amdgcn_exp2f(s1[i] * KSCALE); ls[1][i] += p1;
                p_s[wv][idx] = (bf16)p0;     // rb0 -> LDS now
                p1f[nb][i] = p1;             // rb1 carried in regs
            }
        }

        __builtin_amdgcn_sched_barrier(0);
        __builtin_amdgcn_s_barrier();                 // barC: k2 reads done
        __builtin_amdgcn_sched_barrier(0);
        if (more) {
            const bf16* Kn = Kg + ((size_t)b * 64 + kt + 1) * 8192;
#pragma unroll
            for (int i = 0; i < 4; ++i) {
                const int off = (wv * 4 + i) * 512 + doff;
                dma16(Kn + off, &k2[off]);
            }
        }
        __builtin_amdgcn_sched_barrier(0);

        // ---- PV rb0 ----
        {
            bf16x8 pf0[2];
#pragma unroll
            for (int kc = 0; kc < 2; ++kc) {
                const int kvg = kc * 4 + quad;
                pf0[kc] = *(const bf16x8*)&p_s[wv][(l16 * 8 + ((kvg ^ l16) & 7)) * 8];
            }
#pragma unroll
            for (int kc = 0; kc < 2; ++kc) {
                const int kvg = kc * 4 + quad;
#pragma unroll
                for (int d = 0; d < 8; ++d) {
                    bf16x8 bv = *(const bf16x8*)&vt2[cur][(kvg * 128 + ((d * 16 + l16) ^ kvg)) * 8];
                    o[0][d] = __builtin_amdgcn_mfma_f32_16x16x32_bf16(pf0[kc], bv, o[0][d], 0, 0, 0);
                }
            }
        }
        // ---- scatter rb1's P (wave-private p_s reuse; DS ops in-order per wave) ----
#pragma unroll
        for (int nb = 0; nb < 4; ++nb) {
            const int col = nb * 16 + l16;
#pragma unroll
            for (int i = 0; i < 4; ++i) {
                const int row = quad * 4 + i;
                const int idx = (row * 8 + (((col >> 3) ^ row) & 7)) * 8 + (col & 7);
                p_s[wv][idx] = (bf16)p1f[nb][i];
            }
        }
        // ---- PV rb1 ----
        {
            bf16x8 pf1[2];
#pragma unroll
            for (int kc = 0; kc < 2; ++kc) {
                const int kvg = kc * 4 + quad;
                pf1[kc] = *(const bf16x8*)&p_s[wv][(l16 * 8 + ((kvg ^ l16) & 7)) * 8];
            }
#pragma unroll
            for (int kc = 0; kc < 2; ++kc) {
                const int kvg = kc * 4 + quad;
#pragma unroll
                for (int d = 0; d < 8; ++d) {
                    bf16x8 bv = *(const bf16x8*)&vt2[cur][(kvg * 128 + ((d * 16 + l16) ^ kvg)) * 8];
                    o[1][d] = __builtin_amdgcn_mfma_f32_16x16x32_bf16(pf1[kc], bv, o[1][d], 0, 0, 0);
                }
            }
        }
    }

    // row sums across the 16 lanes of each quad
#pragma unroll
    for (int rb = 0; rb < 2; ++rb)
#pragma unroll
        for (int i = 0; i < 4; ++i)
#pragma unroll
            for (int off = 1; off < 16; off <<= 1)
                ls[rb][i] += __shfl_xor(ls[rb][i], off, 64);
    if (l16 == 0) {
#pragma unroll
        for (int rb = 0; rb < 2; ++rb)
#pragma unroll
            for (int i = 0; i < 4; ++i)
                lsum[(size_t)sp * (BATCH * NTOK) + (size_t)b * NTOK
                     + q0 + wv * 32 + rb * 16 + quad * 4 + i] = ls[rb][i];
    }
    // bf16 partials in fragment order: [sp][qb][b][wv][rb][d][i][lane]
    bf16* op = Op + (((((size_t)sp * 32 + qb) * BATCH + b) * 4 + wv) * (2 * 8 * 4 * 64));
#pragma unroll
    for (int rb = 0; rb < 2; ++rb)
#pragma unroll
        for (int d = 0; d < 8; ++d)
#pragma unroll
            for (int i = 0; i < 4; ++i)
                op[((rb * 8 + d) * 4 + i) * 64 + lane] = (bf16)o[rb][d][i];
}

// ---------------------------------------------------------------------------
// Combine: out = sum_sp(Op) / sum_sp(lsum). One thread = 4 consecutive output
// floats of one row -> float4 fully-coalesced stores; b64 partial reads.
// BUGFIX vs R5: per-(qb,b,wv) block stride is 4096 elems (2*8*4*64), not 2048.
// ---------------------------------------------------------------------------
__global__ __launch_bounds__(256) void combine_kernel(
    const bf16* __restrict__ Op, const float* __restrict__ lsum,
    float* __restrict__ out, int nsplit)
{
    const int g  = blockIdx.x * 256 + threadIdx.x;   // [0, 524288)
    const int rg = g >> 5;                           // global row [0,16384)
    const int cl = (g & 31) << 2;                    // col base 0,4,...,124
    const int b  = rg >> 12, n = rg & 4095;
    const int qb = n >> 7, wvv = (n >> 5) & 3, rb = (n >> 4) & 1;
    const int quad = (n >> 2) & 3, i = n & 3;
    const int d = cl >> 4, l0 = cl & 15;

    const size_t base = (((size_t)qb * BATCH + b) * 4 + wvv) * 4096
                        + (size_t)((rb * 8 + d) * 4 + i) * 64 + quad * 16 + l0;
    const size_t spstride = (size_t)32 * BATCH * 4 * 4096;  // 2M elems

    float a0 = 0.f, a1 = 0.f, a2 = 0.f, a3 = 0.f;
    for (int s = 0; s < nsplit; ++s) {
        bf16x4 v = *(const bf16x4*)&Op[(size_t)s * spstride + base];
        a0 += (float)v[0]; a1 += (float)v[1]; a2 += (float)v[2]; a3 += (float)v[3];
    }
    float l = 0.f;
    for (int s = 0; s < nsplit; ++s)
        l += lsum[(size_t)s * (BATCH * NTOK) + rg];
    const float inv = 1.0f / l;
    f32x4 r = {a0 * inv, a1 * inv, a2 * inv, a3 * inv};
    *(f32x4*)&out[(size_t)rg * CDIM + cl] = r;
}

// ---------------------------------------------------------------------------
extern "C" void kernel_launch(void* const* d_in, const int* in_sizes, int n_in,
                              void* d_out, int out_size, void* d_ws, size_t ws_size,
                              hipStream_t stream)
{
    const float* x  = (const float*)d_in[0];
    const float* Wq = (const float*)d_in[1];
    const float* Wk = (const float*)d_in[2];
    const float* Wv = (const float*)d_in[3];
    float* out = (float*)d_out;

    // ws: Q 4M | Kimg 4M | Vimg 4M | lsum 512K | Wimg 128K | Op nsplit*4M (bf16)
    char* ws = (char*)d_ws;
    bf16*  Qg   = (bf16*)ws;
    bf16*  Kg   = (bf16*)(ws + (4u << 20));
    bf16*  Vtg  = (bf16*)(ws + (8u << 20));
    float* lsum = (float*)(ws + (12u << 20));
    bf16*  Wimg = (bf16*)(ws + (12u << 20) + (512u << 10));
    bf16*  Op   = (bf16*)(ws + (12u << 20) + (640u << 10));

    const size_t base = (12u << 20) + (640u << 10);
    const size_t MB4  = 4u << 20;
    int nsplit = (ws_size >= base + 8 * MB4) ? 8
               : (ws_size >= base + 4 * MB4) ? 4 : 2;

    hipLaunchKernelGGL(prep_kernel, dim3(16, 3), dim3(256), 0, stream,
                       Wq, Wk, Wv, Wimg);
    hipLaunchKernelGGL(proj_kernel, dim3(64, BATCH, 3), dim3(256), 0, stream,
                       x, Wimg, Qg, Kg, Vtg);
    hipLaunchKernelGGL(attn_kernel, dim3(32, BATCH, nsplit), dim3(256), 0, stream,
                       Qg, Kg, Vtg, Op, lsum, nsplit);
    hipLaunchKernelGGL(combine_kernel, dim3(2048), dim3(256), 0, stream,
                       Op, lsum, out, nsplit);
}